// Round 2
// baseline (197.128 us; speedup 1.0000x reference)
//
#include <hip/hip_runtime.h>

#define NF   20000
#define NALL 60000
#define NE   640000
#define DD   128
#define AA   64

typedef __attribute__((ext_vector_type(8))) short short8;
typedef __attribute__((ext_vector_type(4))) float f32x4;

__device__ __forceinline__ unsigned short f2b(float x) {
    unsigned int u = __float_as_uint(x);
    return (unsigned short)((u + 0x7FFFu + ((u >> 16) & 1u)) >> 16);  // RNE
}
__device__ __forceinline__ float b2f(unsigned short v) {
    return __uint_as_float(((unsigned int)v) << 16);
}
__device__ __forceinline__ short8 pack8(float4 a, float4 b) {
    short8 r;
    r[0]=(short)f2b(a.x); r[1]=(short)f2b(a.y); r[2]=(short)f2b(a.z); r[3]=(short)f2b(a.w);
    r[4]=(short)f2b(b.x); r[5]=(short)f2b(b.y); r[6]=(short)f2b(b.z); r[7]=(short)f2b(b.w);
    return r;
}

// ---- K1: fused conv+proj. Loads fp32 embs, converts (writes embB bf16),
// computes P1 = feat@W1+bias, P2 = [feat;hid]@W2 (bf16) via MFMA. W from fp32 on the fly.
__global__ __launch_bounds__(256) void embproj_kernel(
    const float* __restrict__ featEmb, const float* __restrict__ hidEmb,
    const float* __restrict__ wK, const float* __restrict__ bias,
    unsigned short* __restrict__ embB,
    unsigned short* __restrict__ P1b, unsigned short* __restrict__ P2b)
{
    const int wave = threadIdx.x >> 6, lane = threadIdx.x & 63;
    const int rt = blockIdx.x * 4 + wave;
    if (rt >= NALL / 16) return;
    const int row0 = rt * 16;
    const int m = lane & 15, quad = lane >> 4;

    const int row = row0 + m;   // NF % 16 == 0: no tile straddles the feat/hid boundary
    const float* src = (row < NF) ? featEmb + (size_t)row * DD
                                  : hidEmb + (size_t)(row - NF) * DD;
    short8 afr[4];
    #pragma unroll
    for (int kc = 0; kc < 4; ++kc) {
        float4 a0 = *(const float4*)&src[kc * 32 + quad * 8];
        float4 a1 = *(const float4*)&src[kc * 32 + quad * 8 + 4];
        afr[kc] = pack8(a0, a1);
        *(short8*)&embB[(size_t)row * DD + kc * 32 + quad * 8] = afr[kc];
    }

    const float* W2 = wK + DD * AA;   // rows 128..255 of w_kernel
    #pragma unroll
    for (int nt = 0; nt < 4; ++nt) {
        f32x4 acc = {0.f, 0.f, 0.f, 0.f};
        #pragma unroll
        for (int kc = 0; kc < 4; ++kc) {
            short8 bfr;
            #pragma unroll
            for (int j = 0; j < 8; ++j)
                bfr[j] = (short)f2b(W2[(kc * 32 + quad * 8 + j) * AA + nt * 16 + m]);
            acc = __builtin_amdgcn_mfma_f32_16x16x32_bf16(afr[kc], bfr, acc, 0, 0, 0);
        }
        #pragma unroll
        for (int r = 0; r < 4; ++r)   // C/D: col=lane&15, row=quad*4+r
            P2b[(size_t)(row0 + quad * 4 + r) * AA + nt * 16 + m] = f2b(acc[r]);
    }
    if (row0 < NF) {
        #pragma unroll
        for (int nt = 0; nt < 4; ++nt) {
            f32x4 acc = {0.f, 0.f, 0.f, 0.f};
            #pragma unroll
            for (int kc = 0; kc < 4; ++kc) {
                short8 bfr;
                #pragma unroll
                for (int j = 0; j < 8; ++j)
                    bfr[j] = (short)f2b(wK[(kc * 32 + quad * 8 + j) * AA + nt * 16 + m]);
                acc = __builtin_amdgcn_mfma_f32_16x16x32_bf16(afr[kc], bfr, acc, 0, 0, 0);
            }
            const float bv = bias[nt * 16 + m];
            #pragma unroll
            for (int r = 0; r < 4; ++r)
                P1b[(size_t)(row0 + quad * 4 + r) * AA + nt * 16 + m] = f2b(acc[r] + bv);
        }
    }
}

// ---- K2: rowptr[f] = lower_bound(cp, f). Boundary scatter, cp sorted.
__global__ __launch_bounds__(256) void rowptr_kernel(
    const int* __restrict__ cp, int* __restrict__ rowptr)
{
    const int e = blockIdx.x * 256 + threadIdx.x;
    const int cur = cp[e];
    const int prev = (e == 0) ? -1 : cp[e - 1];
    for (int f = prev + 1; f <= cur; ++f) rowptr[f] = e;
    if (e == NE - 1)
        for (int f = cur + 1; f <= NF; ++f) rowptr[f] = NE;
}

// ---- K3+K4 fused: per-feature scoring + segment softmax + context -> ctxT.
// Block = 512 threads (8 waves), 32 consecutive features, dynamic wave->feature
// queue (LDS atomic counter) to kill barrier imbalance. Per feature:
//   phase 1 (chunk of <=64 edges): 8 edges/wave-iter, 8 lanes/edge x 8 cols/lane.
//     P2 row gather = uint4/lane (8 rows = 1KB per load instr), tanh via exp+rcp,
//     dot with u by 3-step shfl_xor reduce; scores -> per-wave LDS buffer.
//   phase 2: 8-deep embB row gather-accumulate (as before), scores from LDS.
// Epilogue: LDS transpose tile -> full 64B-line ctxT stores (no RMW).
__global__ __launch_bounds__(512) void scorectx_kernel(
    const unsigned short* __restrict__ embB,
    const unsigned short* __restrict__ P1b, const unsigned short* __restrict__ P2b,
    const float* __restrict__ uK, const float* __restrict__ corr,
    const int* __restrict__ rowptr, const int* __restrict__ fci,
    unsigned short* __restrict__ ctxT)
{
    __shared__ unsigned int tile[64 * 33];   // [dpair][feat]: lo16=row 2d, hi16=row 2d+1
    __shared__ float sbuf[8 * 64];           // per-wave score chunk
    __shared__ int wcnt;
    const int lane = threadIdx.x & 63;
    const int wave = threadIdx.x >> 6;       // 0..7
    const int f0 = blockIdx.x * 32;
    if (threadIdx.x == 0) wcnt = 0;
    __syncthreads();

    const int c = lane & 7, g = lane >> 3;   // scoring: col-octet c, edge-slot g
    float uv[8];
    #pragma unroll
    for (int k = 0; k < 8; ++k) uv[k] = uK[c * 8 + k];
    float* swb = &sbuf[wave * 64];

    for (;;) {
        int fl = 0;
        if (lane == 0) fl = atomicAdd(&wcnt, 1);
        fl = __shfl(fl, 0);
        if (fl >= 32) break;
        const int f = f0 + fl;
        const int start = rowptr[f], end = rowptr[f + 1];

        float p1v[8];   // P1 row, once per feature
        {
            uint4 q = *(const uint4*)&P1b[(size_t)f * AA + c * 8];
            unsigned int qq[4] = {q.x, q.y, q.z, q.w};
            #pragma unroll
            for (int k = 0; k < 4; ++k) {
                p1v[2*k]   = b2f((unsigned short)(qq[k] & 0xFFFF));
                p1v[2*k+1] = b2f((unsigned short)(qq[k] >> 16));
            }
        }

        float acc0 = 0.f, acc1 = 0.f, den = 0.f;
        for (int cb = start; cb < end; cb += 64) {
            const int n = min(64, end - cb);
            // ---- phase 1: scores for edges [cb, cb+n)
            for (int eb = 0; eb < n; eb += 8) {
                const bool valid = (eb + g < n);
                const int ec = valid ? (cb + eb + g) : (end - 1);
                const int idx = fci[ec];
                uint4 q = *(const uint4*)&P2b[(size_t)idx * AA + c * 8];
                unsigned int qq[4] = {q.x, q.y, q.z, q.w};
                float part = 0.f;
                #pragma unroll
                for (int k = 0; k < 4; ++k) {
                    const float x0 = p1v[2*k]   + b2f((unsigned short)(qq[k] & 0xFFFF));
                    const float x1 = p1v[2*k+1] + b2f((unsigned short)(qq[k] >> 16));
                    const float t0 = 1.f - 2.f * __builtin_amdgcn_rcpf(__expf(2.f * x0) + 1.f);
                    const float t1 = 1.f - 2.f * __builtin_amdgcn_rcpf(__expf(2.f * x1) + 1.f);
                    part = fmaf(t0, uv[2*k], part);
                    part = fmaf(t1, uv[2*k+1], part);
                }
                part += __shfl_xor(part, 1);
                part += __shfl_xor(part, 2);
                part += __shfl_xor(part, 4);
                float s = __expf(part) * corr[ec];
                if (!valid) s = 0.f;
                if (c == 0) swb[eb + g] = s;
            }
            asm volatile("s_waitcnt lgkmcnt(0)" ::: "memory");  // wave-local LDS visibility

            // ---- phase 2: gather-accumulate embB rows
            int e2 = 0;
            for (; e2 + 8 <= n; e2 += 8) {
                int   ii[8]; float ss[8]; unsigned int vv[8];
                #pragma unroll
                for (int j = 0; j < 8; ++j) ii[j] = fci[cb + e2 + j];
                #pragma unroll
                for (int j = 0; j < 8; ++j) ss[j] = swb[e2 + j];
                #pragma unroll
                for (int j = 0; j < 8; ++j)
                    vv[j] = *(const unsigned int*)&embB[(size_t)ii[j] * DD + lane * 2];
                #pragma unroll
                for (int j = 0; j < 8; ++j) {
                    acc0 = fmaf(ss[j], b2f((unsigned short)(vv[j] & 0xFFFF)), acc0);
                    acc1 = fmaf(ss[j], b2f((unsigned short)(vv[j] >> 16)),    acc1);
                    den += ss[j];
                }
            }
            for (; e2 < n; ++e2) {
                const int i0 = fci[cb + e2]; const float s0 = swb[e2];
                const unsigned int v0 = *(const unsigned int*)&embB[(size_t)i0 * DD + lane * 2];
                acc0 = fmaf(s0, b2f((unsigned short)(v0 & 0xFFFF)), acc0);
                acc1 = fmaf(s0, b2f((unsigned short)(v0 >> 16)),    acc1);
                den += s0;
            }
        }
        const float inv = (den != 0.f) ? 1.f / den : 0.f;
        // banks: (lane*33+fl)%32 -> 2-way per wave store = free
        tile[lane * 33 + fl] = ((unsigned int)f2b(acc1 * inv) << 16) | f2b(acc0 * inv);
    }
    __syncthreads();

    // Write phase: 128 rows x 32 feats = 2048 u32; 512 threads -> one uint4 each.
    // 4 consecutive threads cover one full 64B line of a ctxT row (no RMW).
    const int tt = threadIdx.x;
    const int r = tt >> 2, qd = tt & 3;
    const int dpair = r >> 1, half = r & 1;
    unsigned int o[4];
    #pragma unroll
    for (int j = 0; j < 4; ++j) {
        const int cc = qd * 4 + j;
        const unsigned int v0 = tile[dpair * 33 + 2 * cc];
        const unsigned int v1 = tile[dpair * 33 + 2 * cc + 1];
        o[j] = half ? ((v1 & 0xFFFF0000u) | (v0 >> 16))
                    : ((v1 << 16) | (v0 & 0xFFFFu));
    }
    uint4 ov = {o[0], o[1], o[2], o[3]};
    *(uint4*)&ctxT[(size_t)r * NF + f0 + qd * 8] = ov;
}

// ---- K5: out[256,128] = values @ ctx via MFMA; values split hi/lo bf16 (exact).
__global__ __launch_bounds__(256) void outmm_kernel(
    const float* __restrict__ values, const unsigned short* __restrict__ ctxT,
    float* __restrict__ out)
{
    const int wave = threadIdx.x >> 6, lane = threadIdx.x & 63;
    const int m = lane & 15, quad = lane >> 4;
    const int mgroup = blockIdx.x & 3, kchunk = blockIdx.x >> 2;
    const int m0 = mgroup * 64 + wave * 16;
    const int k0 = kchunk * 160;

    f32x4 acc[8];
    #pragma unroll
    for (int nt = 0; nt < 8; ++nt) acc[nt] = (f32x4){0.f, 0.f, 0.f, 0.f};

    for (int ks = 0; ks < 5; ++ks) {
        const int kk = k0 + ks * 32 + quad * 8;
        const float* ap = &values[(size_t)(m0 + m) * NF + kk];
        float4 a0 = *(const float4*)ap;
        float4 a1 = *(const float4*)(ap + 4);
        float av[8] = {a0.x, a0.y, a0.z, a0.w, a1.x, a1.y, a1.z, a1.w};
        short8 ahi, alo;
        #pragma unroll
        for (int j = 0; j < 8; ++j) {
            unsigned short hv = f2b(av[j]);
            ahi[j] = (short)hv;
            alo[j] = (short)f2b(av[j] - b2f(hv));
        }
        #pragma unroll
        for (int nt = 0; nt < 8; ++nt) {
            short8 b = *(const short8*)&ctxT[(size_t)(nt * 16 + m) * NF + kk];
            acc[nt] = __builtin_amdgcn_mfma_f32_16x16x32_bf16(ahi, b, acc[nt], 0, 0, 0);
            acc[nt] = __builtin_amdgcn_mfma_f32_16x16x32_bf16(alo, b, acc[nt], 0, 0, 0);
        }
    }
    #pragma unroll
    for (int nt = 0; nt < 8; ++nt)
        #pragma unroll
        for (int r = 0; r < 4; ++r)
            atomicAdd(&out[(size_t)(m0 + quad * 4 + r) * DD + nt * 16 + m], acc[nt][r]);
}

extern "C" void kernel_launch(void* const* d_in, const int* in_sizes, int n_in,
                              void* d_out, int out_size, void* d_ws, size_t ws_size,
                              hipStream_t stream)
{
    const float* values  = (const float*)d_in[0];
    const float* featEmb = (const float*)d_in[1];
    const float* hidEmb  = (const float*)d_in[2];
    const float* wK      = (const float*)d_in[3];
    const float* wB      = (const float*)d_in[4];
    const float* uK      = (const float*)d_in[5];
    const float* corr    = (const float*)d_in[6];
    const int* cp        = (const int*)d_in[7];
    const int* fci       = (const int*)d_in[8];
    float* out = (float*)d_out;

    // ws layout (bytes, 16B-aligned):
    char* ws = (char*)d_ws;
    unsigned short* embB  = (unsigned short*)(ws);                   // 15,360,000
    unsigned short* P1b   = (unsigned short*)(ws + 15360000);        //  2,560,000
    unsigned short* P2b   = (unsigned short*)(ws + 17920000);        //  7,680,000
    unsigned short* ctxT  = (unsigned short*)(ws + 28160000);        //  5,120,000
    int*            rowptr= (int*)          (ws + 33280000);         //     80,004  (total 33.4 MB)

    embproj_kernel <<<938,  256, 0, stream>>>(featEmb, hidEmb, wK, wB, embB, P1b, P2b);
    rowptr_kernel  <<<2500, 256, 0, stream>>>(cp, rowptr);
    scorectx_kernel<<<625,  512, 0, stream>>>(embB, P1b, P2b, uK, corr, rowptr, fci, ctxT);
    hipMemsetAsync(d_out, 0, (size_t)out_size * sizeof(float), stream);
    outmm_kernel   <<<500,  256, 0, stream>>>(values, ctxT, out);
}

// Round 3
// 195.996 us; speedup vs baseline: 1.0058x; 1.0058x over previous
//
#include <hip/hip_runtime.h>

#define NF   20000
#define NALL 60000
#define NE   640000
#define DD   128
#define AA   64

typedef __attribute__((ext_vector_type(8))) short short8;
typedef __attribute__((ext_vector_type(4))) float f32x4;

__device__ __forceinline__ unsigned short f2b(float x) {
    unsigned int u = __float_as_uint(x);
    return (unsigned short)((u + 0x7FFFu + ((u >> 16) & 1u)) >> 16);  // RNE
}
__device__ __forceinline__ float b2f(unsigned short v) {
    return __uint_as_float(((unsigned int)v) << 16);
}
__device__ __forceinline__ short8 pack8(float4 a, float4 b) {
    short8 r;
    r[0]=(short)f2b(a.x); r[1]=(short)f2b(a.y); r[2]=(short)f2b(a.z); r[3]=(short)f2b(a.w);
    r[4]=(short)f2b(b.x); r[5]=(short)f2b(b.y); r[6]=(short)f2b(b.z); r[7]=(short)f2b(b.w);
    return r;
}

// ---- K1: fused conv+proj. Loads fp32 embs, converts (writes embB bf16),
// computes P1 = feat@W1+bias, P2 = [feat;hid]@W2 (bf16) via MFMA. W from fp32 on the fly.
__global__ __launch_bounds__(256) void embproj_kernel(
    const float* __restrict__ featEmb, const float* __restrict__ hidEmb,
    const float* __restrict__ wK, const float* __restrict__ bias,
    unsigned short* __restrict__ embB,
    unsigned short* __restrict__ P1b, unsigned short* __restrict__ P2b)
{
    const int wave = threadIdx.x >> 6, lane = threadIdx.x & 63;
    const int rt = blockIdx.x * 4 + wave;
    if (rt >= NALL / 16) return;
    const int row0 = rt * 16;
    const int m = lane & 15, quad = lane >> 4;

    const int row = row0 + m;   // NF % 16 == 0: no tile straddles the feat/hid boundary
    const float* src = (row < NF) ? featEmb + (size_t)row * DD
                                  : hidEmb + (size_t)(row - NF) * DD;
    short8 afr[4];
    #pragma unroll
    for (int kc = 0; kc < 4; ++kc) {
        float4 a0 = *(const float4*)&src[kc * 32 + quad * 8];
        float4 a1 = *(const float4*)&src[kc * 32 + quad * 8 + 4];
        afr[kc] = pack8(a0, a1);
        *(short8*)&embB[(size_t)row * DD + kc * 32 + quad * 8] = afr[kc];
    }

    const float* W2 = wK + DD * AA;   // rows 128..255 of w_kernel
    #pragma unroll
    for (int nt = 0; nt < 4; ++nt) {
        f32x4 acc = {0.f, 0.f, 0.f, 0.f};
        #pragma unroll
        for (int kc = 0; kc < 4; ++kc) {
            short8 bfr;
            #pragma unroll
            for (int j = 0; j < 8; ++j)
                bfr[j] = (short)f2b(W2[(kc * 32 + quad * 8 + j) * AA + nt * 16 + m]);
            acc = __builtin_amdgcn_mfma_f32_16x16x32_bf16(afr[kc], bfr, acc, 0, 0, 0);
        }
        #pragma unroll
        for (int r = 0; r < 4; ++r)   // C/D: col=lane&15, row=quad*4+r
            P2b[(size_t)(row0 + quad * 4 + r) * AA + nt * 16 + m] = f2b(acc[r]);
    }
    if (row0 < NF) {
        #pragma unroll
        for (int nt = 0; nt < 4; ++nt) {
            f32x4 acc = {0.f, 0.f, 0.f, 0.f};
            #pragma unroll
            for (int kc = 0; kc < 4; ++kc) {
                short8 bfr;
                #pragma unroll
                for (int j = 0; j < 8; ++j)
                    bfr[j] = (short)f2b(wK[(kc * 32 + quad * 8 + j) * AA + nt * 16 + m]);
                acc = __builtin_amdgcn_mfma_f32_16x16x32_bf16(afr[kc], bfr, acc, 0, 0, 0);
            }
            const float bv = bias[nt * 16 + m];
            #pragma unroll
            for (int r = 0; r < 4; ++r)
                P1b[(size_t)(row0 + quad * 4 + r) * AA + nt * 16 + m] = f2b(acc[r] + bv);
        }
    }
}

// ---- K2: rowptr[f] = lower_bound(cp, f). Boundary scatter, cp sorted.
__global__ __launch_bounds__(256) void rowptr_kernel(
    const int* __restrict__ cp, int* __restrict__ rowptr)
{
    const int e = blockIdx.x * 256 + threadIdx.x;
    const int cur = cp[e];
    const int prev = (e == 0) ? -1 : cp[e - 1];
    for (int f = prev + 1; f <= cur; ++f) rowptr[f] = e;
    if (e == NE - 1)
        for (int f = cur + 1; f <= NF; ++f) rowptr[f] = NE;
}

// ---- K3: fused scoring + segment softmax + context -> ctx [NF][128] row-major.
// One INDEPENDENT wave per feature (20000 waves, ~78/CU offered -> occupancy cap).
// No block tile, no barrier, no queue. Per <=64-edge chunk:
//   phase 1: 8 edges/wave-iter, 8 lanes/edge x 8 cols; P2 gather = uint4/lane;
//            tanh via exp+rcp; 3-step shfl_xor dot with u; scores -> wave LDS buf.
//   phase 2: 8-deep embB row gather-accumulate, scores from LDS.
// Store: one full 256B line per feature (64 lanes x u32), no RMW.
__global__ __launch_bounds__(512) void scorectx_kernel(
    const unsigned short* __restrict__ embB,
    const unsigned short* __restrict__ P1b, const unsigned short* __restrict__ P2b,
    const float* __restrict__ uK, const float* __restrict__ corr,
    const int* __restrict__ rowptr, const int* __restrict__ fci,
    unsigned short* __restrict__ ctx)
{
    __shared__ float sbuf[8 * 64];           // per-wave score chunk
    const int lane = threadIdx.x & 63;
    const int wave = threadIdx.x >> 6;       // 0..7
    const int f = blockIdx.x * 8 + wave;     // 2500 blocks * 8 waves = 20000 = NF

    const int c = lane & 7, g = lane >> 3;   // scoring: col-octet c, edge-slot g
    float uv[8];
    #pragma unroll
    for (int k = 0; k < 8; ++k) uv[k] = uK[c * 8 + k];
    float* swb = &sbuf[wave * 64];

    const int start = rowptr[f], end = rowptr[f + 1];

    float p1v[8];   // P1 row, once per feature
    {
        uint4 q = *(const uint4*)&P1b[(size_t)f * AA + c * 8];
        unsigned int qq[4] = {q.x, q.y, q.z, q.w};
        #pragma unroll
        for (int k = 0; k < 4; ++k) {
            p1v[2*k]   = b2f((unsigned short)(qq[k] & 0xFFFF));
            p1v[2*k+1] = b2f((unsigned short)(qq[k] >> 16));
        }
    }

    float acc0 = 0.f, acc1 = 0.f, den = 0.f;
    for (int cb = start; cb < end; cb += 64) {
        const int n = min(64, end - cb);
        // ---- phase 1: scores for edges [cb, cb+n)
        for (int eb = 0; eb < n; eb += 8) {
            const bool valid = (eb + g < n);
            const int ec = valid ? (cb + eb + g) : (end - 1);
            const int idx = fci[ec];
            uint4 q = *(const uint4*)&P2b[(size_t)idx * AA + c * 8];
            unsigned int qq[4] = {q.x, q.y, q.z, q.w};
            float part = 0.f;
            #pragma unroll
            for (int k = 0; k < 4; ++k) {
                const float x0 = p1v[2*k]   + b2f((unsigned short)(qq[k] & 0xFFFF));
                const float x1 = p1v[2*k+1] + b2f((unsigned short)(qq[k] >> 16));
                const float t0 = 1.f - 2.f * __builtin_amdgcn_rcpf(__expf(2.f * x0) + 1.f);
                const float t1 = 1.f - 2.f * __builtin_amdgcn_rcpf(__expf(2.f * x1) + 1.f);
                part = fmaf(t0, uv[2*k], part);
                part = fmaf(t1, uv[2*k+1], part);
            }
            part += __shfl_xor(part, 1);
            part += __shfl_xor(part, 2);
            part += __shfl_xor(part, 4);
            float s = __expf(part) * corr[ec];
            if (!valid) s = 0.f;
            if (c == 0) swb[eb + g] = s;
        }
        asm volatile("s_waitcnt lgkmcnt(0)" ::: "memory");  // wave-local LDS visibility

        // ---- phase 2: gather-accumulate embB rows
        int e2 = 0;
        for (; e2 + 8 <= n; e2 += 8) {
            int   ii[8]; float ss[8]; unsigned int vv[8];
            #pragma unroll
            for (int j = 0; j < 8; ++j) ii[j] = fci[cb + e2 + j];
            #pragma unroll
            for (int j = 0; j < 8; ++j) ss[j] = swb[e2 + j];
            #pragma unroll
            for (int j = 0; j < 8; ++j)
                vv[j] = *(const unsigned int*)&embB[(size_t)ii[j] * DD + lane * 2];
            #pragma unroll
            for (int j = 0; j < 8; ++j) {
                acc0 = fmaf(ss[j], b2f((unsigned short)(vv[j] & 0xFFFF)), acc0);
                acc1 = fmaf(ss[j], b2f((unsigned short)(vv[j] >> 16)),    acc1);
                den += ss[j];
            }
        }
        for (; e2 < n; ++e2) {
            const int i0 = fci[cb + e2]; const float s0 = swb[e2];
            const unsigned int v0 = *(const unsigned int*)&embB[(size_t)i0 * DD + lane * 2];
            acc0 = fmaf(s0, b2f((unsigned short)(v0 & 0xFFFF)), acc0);
            acc1 = fmaf(s0, b2f((unsigned short)(v0 >> 16)),    acc1);
            den += s0;
        }
    }
    const float inv = (den != 0.f) ? 1.f / den : 0.f;
    // dims {2*lane, 2*lane+1} packed -> 64 lanes x u32 = one full 256B line
    *(unsigned int*)&ctx[(size_t)f * DD + 2 * lane] =
        ((unsigned int)f2b(acc1 * inv) << 16) | f2b(acc0 * inv);
}

// ---- K4: transpose ctx [NF][128] -> ctxT [128][NF] (bf16), full-line I/O both sides.
__global__ __launch_bounds__(256) void transpose_kernel(
    const unsigned short* __restrict__ ctx, unsigned short* __restrict__ ctxT)
{
    __shared__ unsigned int tile[64 * 33];   // [dpair][feat]: lo16=row 2d, hi16=row 2d+1
    const int t = threadIdx.x;
    const int f0 = blockIdx.x * 32;
    const int fl = t >> 3, db = t & 7;       // feature-local 0..31, dim-block (16 dims)
    const unsigned int* src = (const unsigned int*)&ctx[(size_t)(f0 + fl) * DD + db * 16];
    uint4 q0 = *(const uint4*)src;           // dims db*16+0..7 (u32 j: dims 2j,2j+1)
    uint4 q1 = *(const uint4*)(src + 4);     // dims db*16+8..15
    unsigned int w[8] = {q0.x, q0.y, q0.z, q0.w, q1.x, q1.y, q1.z, q1.w};
    #pragma unroll
    for (int j = 0; j < 8; ++j)
        tile[(db * 8 + j) * 33 + fl] = w[j];
    __syncthreads();

    const int r = t >> 1, side = t & 1;      // row 0..127, 16-feature half
    const int dpair = r >> 1, odd = r & 1;
    unsigned int o[8];
    #pragma unroll
    for (int i = 0; i < 8; ++i) {
        const int fo = side * 16 + i * 2;
        const unsigned int v0 = tile[dpair * 33 + fo];
        const unsigned int v1 = tile[dpair * 33 + fo + 1];
        o[i] = odd ? ((v1 & 0xFFFF0000u) | (v0 >> 16))
                   : ((v1 << 16) | (v0 & 0xFFFFu));
    }
    uint4 a = {o[0], o[1], o[2], o[3]}, b = {o[4], o[5], o[6], o[7]};
    *(uint4*)&ctxT[(size_t)r * NF + f0 + side * 16]     = a;
    *(uint4*)&ctxT[(size_t)r * NF + f0 + side * 16 + 8] = b;
}

// ---- K5: out[256,128] = values @ ctx via MFMA; values split hi/lo bf16 (exact).
__global__ __launch_bounds__(256) void outmm_kernel(
    const float* __restrict__ values, const unsigned short* __restrict__ ctxT,
    float* __restrict__ out)
{
    const int wave = threadIdx.x >> 6, lane = threadIdx.x & 63;
    const int m = lane & 15, quad = lane >> 4;
    const int mgroup = blockIdx.x & 3, kchunk = blockIdx.x >> 2;
    const int m0 = mgroup * 64 + wave * 16;
    const int k0 = kchunk * 160;

    f32x4 acc[8];
    #pragma unroll
    for (int nt = 0; nt < 8; ++nt) acc[nt] = (f32x4){0.f, 0.f, 0.f, 0.f};

    for (int ks = 0; ks < 5; ++ks) {
        const int kk = k0 + ks * 32 + quad * 8;
        const float* ap = &values[(size_t)(m0 + m) * NF + kk];
        float4 a0 = *(const float4*)ap;
        float4 a1 = *(const float4*)(ap + 4);
        float av[8] = {a0.x, a0.y, a0.z, a0.w, a1.x, a1.y, a1.z, a1.w};
        short8 ahi, alo;
        #pragma unroll
        for (int j = 0; j < 8; ++j) {
            unsigned short hv = f2b(av[j]);
            ahi[j] = (short)hv;
            alo[j] = (short)f2b(av[j] - b2f(hv));
        }
        #pragma unroll
        for (int nt = 0; nt < 8; ++nt) {
            short8 b = *(const short8*)&ctxT[(size_t)(nt * 16 + m) * NF + kk];
            acc[nt] = __builtin_amdgcn_mfma_f32_16x16x32_bf16(ahi, b, acc[nt], 0, 0, 0);
            acc[nt] = __builtin_amdgcn_mfma_f32_16x16x32_bf16(alo, b, acc[nt], 0, 0, 0);
        }
    }
    #pragma unroll
    for (int nt = 0; nt < 8; ++nt)
        #pragma unroll
        for (int r = 0; r < 4; ++r)
            atomicAdd(&out[(size_t)(m0 + quad * 4 + r) * DD + nt * 16 + m], acc[nt][r]);
}

extern "C" void kernel_launch(void* const* d_in, const int* in_sizes, int n_in,
                              void* d_out, int out_size, void* d_ws, size_t ws_size,
                              hipStream_t stream)
{
    const float* values  = (const float*)d_in[0];
    const float* featEmb = (const float*)d_in[1];
    const float* hidEmb  = (const float*)d_in[2];
    const float* wK      = (const float*)d_in[3];
    const float* wB      = (const float*)d_in[4];
    const float* uK      = (const float*)d_in[5];
    const float* corr    = (const float*)d_in[6];
    const int* cp        = (const int*)d_in[7];
    const int* fci       = (const int*)d_in[8];
    float* out = (float*)d_out;

    // ws layout (bytes, 16B-aligned):
    char* ws = (char*)d_ws;
    unsigned short* embB  = (unsigned short*)(ws);                   // 15,360,000
    unsigned short* P1b   = (unsigned short*)(ws + 15360000);        //  2,560,000
    unsigned short* P2b   = (unsigned short*)(ws + 17920000);        //  7,680,000
    unsigned short* ctx   = (unsigned short*)(ws + 25600000);        //  5,120,000
    unsigned short* ctxT  = (unsigned short*)(ws + 30720000);        //  5,120,000
    int*            rowptr= (int*)          (ws + 35840000);         //     80,004  (total ~35.9 MB)

    embproj_kernel  <<<938,  256, 0, stream>>>(featEmb, hidEmb, wK, wB, embB, P1b, P2b);
    rowptr_kernel   <<<2500, 256, 0, stream>>>(cp, rowptr);
    scorectx_kernel <<<2500, 512, 0, stream>>>(embB, P1b, P2b, uK, corr, rowptr, fci, ctx);
    transpose_kernel<<<625,  256, 0, stream>>>(ctx, ctxT);
    hipMemsetAsync(d_out, 0, (size_t)out_size * sizeof(float), stream);
    outmm_kernel    <<<500,  256, 0, stream>>>(values, ctxT, out);
}

// Round 4
// 187.649 us; speedup vs baseline: 1.0505x; 1.0445x over previous
//
#include <hip/hip_runtime.h>

#define NF   20000
#define NALL 60000
#define NE   640000
#define DD   128
#define AA   64

typedef __attribute__((ext_vector_type(8))) short short8;
typedef __attribute__((ext_vector_type(4))) float f32x4;

__device__ __forceinline__ unsigned short f2b(float x) {
    unsigned int u = __float_as_uint(x);
    return (unsigned short)((u + 0x7FFFu + ((u >> 16) & 1u)) >> 16);  // RNE
}
__device__ __forceinline__ float b2f(unsigned short v) {
    return __uint_as_float(((unsigned int)v) << 16);
}
__device__ __forceinline__ short8 pack8(float4 a, float4 b) {
    short8 r;
    r[0]=(short)f2b(a.x); r[1]=(short)f2b(a.y); r[2]=(short)f2b(a.z); r[3]=(short)f2b(a.w);
    r[4]=(short)f2b(b.x); r[5]=(short)f2b(b.y); r[6]=(short)f2b(b.z); r[7]=(short)f2b(b.w);
    return r;
}

// ---- K1: fused conv+proj. Loads fp32 embs, converts (writes embB bf16),
// computes P1 = feat@W1+bias, P2 = [feat;hid]@W2 (bf16) via MFMA. W from fp32 on the fly.
__global__ __launch_bounds__(256) void embproj_kernel(
    const float* __restrict__ featEmb, const float* __restrict__ hidEmb,
    const float* __restrict__ wK, const float* __restrict__ bias,
    unsigned short* __restrict__ embB,
    unsigned short* __restrict__ P1b, unsigned short* __restrict__ P2b)
{
    const int wave = threadIdx.x >> 6, lane = threadIdx.x & 63;
    const int rt = blockIdx.x * 4 + wave;
    if (rt >= NALL / 16) return;
    const int row0 = rt * 16;
    const int m = lane & 15, quad = lane >> 4;

    const int row = row0 + m;   // NF % 16 == 0: no tile straddles the feat/hid boundary
    const float* src = (row < NF) ? featEmb + (size_t)row * DD
                                  : hidEmb + (size_t)(row - NF) * DD;
    short8 afr[4];
    #pragma unroll
    for (int kc = 0; kc < 4; ++kc) {
        float4 a0 = *(const float4*)&src[kc * 32 + quad * 8];
        float4 a1 = *(const float4*)&src[kc * 32 + quad * 8 + 4];
        afr[kc] = pack8(a0, a1);
        *(short8*)&embB[(size_t)row * DD + kc * 32 + quad * 8] = afr[kc];
    }

    const float* W2 = wK + DD * AA;   // rows 128..255 of w_kernel
    #pragma unroll
    for (int nt = 0; nt < 4; ++nt) {
        f32x4 acc = {0.f, 0.f, 0.f, 0.f};
        #pragma unroll
        for (int kc = 0; kc < 4; ++kc) {
            short8 bfr;
            #pragma unroll
            for (int j = 0; j < 8; ++j)
                bfr[j] = (short)f2b(W2[(kc * 32 + quad * 8 + j) * AA + nt * 16 + m]);
            acc = __builtin_amdgcn_mfma_f32_16x16x32_bf16(afr[kc], bfr, acc, 0, 0, 0);
        }
        #pragma unroll
        for (int r = 0; r < 4; ++r)   // C/D: col=lane&15, row=quad*4+r
            P2b[(size_t)(row0 + quad * 4 + r) * AA + nt * 16 + m] = f2b(acc[r]);
    }
    if (row0 < NF) {
        #pragma unroll
        for (int nt = 0; nt < 4; ++nt) {
            f32x4 acc = {0.f, 0.f, 0.f, 0.f};
            #pragma unroll
            for (int kc = 0; kc < 4; ++kc) {
                short8 bfr;
                #pragma unroll
                for (int j = 0; j < 8; ++j)
                    bfr[j] = (short)f2b(wK[(kc * 32 + quad * 8 + j) * AA + nt * 16 + m]);
                acc = __builtin_amdgcn_mfma_f32_16x16x32_bf16(afr[kc], bfr, acc, 0, 0, 0);
            }
            const float bv = bias[nt * 16 + m];
            #pragma unroll
            for (int r = 0; r < 4; ++r)
                P1b[(size_t)(row0 + quad * 4 + r) * AA + nt * 16 + m] = f2b(acc[r] + bv);
        }
    }
}

// ---- K2: rowptr[f] = lower_bound(cp, f). Boundary scatter, cp sorted.
__global__ __launch_bounds__(256) void rowptr_kernel(
    const int* __restrict__ cp, int* __restrict__ rowptr)
{
    const int e = blockIdx.x * 256 + threadIdx.x;
    const int cur = cp[e];
    const int prev = (e == 0) ? -1 : cp[e - 1];
    for (int f = prev + 1; f <= cur; ++f) rowptr[f] = e;
    if (e == NE - 1)
        for (int f = cur + 1; f <= NF; ++f) rowptr[f] = NE;
}

// ---- K3: fused scoring + softmax + context -> ctx [NF][128] row-major.
// One independent wave per feature. Single fused loop over 8-edge groups,
// 2-deep software pipeline: PRELOAD(g+1) issued before COMPUTE(g).
// PRELOAD: fci+corr loads, P2 uint4 gather, shfl idx broadcast, embB gathers
// (embB addr depends only on fci -> issued before scoring math, not after).
// COMPUTE: tanh-dot (8 lanes/edge x 8 cols), shfl_xor reduce, shfl score
// broadcast, 8-deep fma accumulate. No LDS at all.
__global__ __launch_bounds__(512) void scorectx_kernel(
    const unsigned short* __restrict__ embB,
    const unsigned short* __restrict__ P1b, const unsigned short* __restrict__ P2b,
    const float* __restrict__ uK, const float* __restrict__ corr,
    const int* __restrict__ rowptr, const int* __restrict__ fci,
    unsigned short* __restrict__ ctx)
{
    const int lane = threadIdx.x & 63;
    const int wave = threadIdx.x >> 6;       // 0..7
    const int f = blockIdx.x * 8 + wave;     // 2500 blocks * 8 waves = 20000 = NF

    const int c = lane & 7, g = lane >> 3;   // col-octet c, edge-slot g
    float uv[8];
    #pragma unroll
    for (int k = 0; k < 8; ++k) uv[k] = uK[c * 8 + k];

    const int start = rowptr[f], end = rowptr[f + 1];

    float p1v[8];   // P1 row, once per feature
    {
        uint4 q = *(const uint4*)&P1b[(size_t)f * AA + c * 8];
        unsigned int qq[4] = {q.x, q.y, q.z, q.w};
        #pragma unroll
        for (int k = 0; k < 4; ++k) {
            p1v[2*k]   = b2f((unsigned short)(qq[k] & 0xFFFF));
            p1v[2*k+1] = b2f((unsigned short)(qq[k] >> 16));
        }
    }

    float acc0 = 0.f, acc1 = 0.f, den = 0.f;

    if (start < end) {
        // pipeline registers: current (A) and next (B)
        uint4 qA, qB;                 // P2 fragment for my edge (e+g)
        unsigned int vvA[8], vvB[8];  // embB row u32 for edges 0..7 of group
        float crA, crB;
        bool vaA, vaB;

        // PRELOAD group at edge base e into (q,vv,cr,va)
        #define PRELOAD(e_, q_, vv_, cr_, va_)                                         \
        {                                                                              \
            va_ = ((e_) + g) < end;                                                    \
            const int ec = va_ ? ((e_) + g) : (end - 1);                               \
            const int idx = fci[ec];                                                   \
            cr_ = corr[ec];                                                            \
            q_ = *(const uint4*)&P2b[(size_t)idx * AA + c * 8];                        \
            _Pragma("unroll")                                                          \
            for (int j = 0; j < 8; ++j) {                                              \
                const int ij = __shfl(idx, j * 8);                                     \
                vv_[j] = *(const unsigned int*)&embB[(size_t)ij * DD + lane * 2];      \
            }                                                                          \
        }

        #define COMPUTE(q_, vv_, cr_, va_)                                             \
        {                                                                              \
            unsigned int qq[4] = {q_.x, q_.y, q_.z, q_.w};                             \
            float part = 0.f;                                                          \
            _Pragma("unroll")                                                          \
            for (int k = 0; k < 4; ++k) {                                              \
                const float x0 = p1v[2*k]   + b2f((unsigned short)(qq[k] & 0xFFFF));   \
                const float x1 = p1v[2*k+1] + b2f((unsigned short)(qq[k] >> 16));      \
                const float t0 = 1.f - 2.f * __builtin_amdgcn_rcpf(__expf(2.f * x0) + 1.f); \
                const float t1 = 1.f - 2.f * __builtin_amdgcn_rcpf(__expf(2.f * x1) + 1.f); \
                part = fmaf(t0, uv[2*k], part);                                        \
                part = fmaf(t1, uv[2*k+1], part);                                      \
            }                                                                          \
            part += __shfl_xor(part, 1);                                               \
            part += __shfl_xor(part, 2);                                               \
            part += __shfl_xor(part, 4);                                               \
            float s = __expf(part) * cr_;                                              \
            if (!va_) s = 0.f;                                                         \
            _Pragma("unroll")                                                          \
            for (int j = 0; j < 8; ++j) {                                              \
                const float sj = __shfl(s, j * 8);                                     \
                acc0 = fmaf(sj, b2f((unsigned short)(vv_[j] & 0xFFFF)), acc0);         \
                acc1 = fmaf(sj, b2f((unsigned short)(vv_[j] >> 16)),    acc1);         \
                den += sj;                                                             \
            }                                                                          \
        }

        int e = start;
        PRELOAD(e, qA, vvA, crA, vaA);
        e += 8;
        for (; e < end; e += 16) {
            PRELOAD(e, qB, vvB, crB, vaB);
            COMPUTE(qA, vvA, crA, vaA);
            if (e + 8 < end) {
                PRELOAD(e + 8, qA, vvA, crA, vaA);
                COMPUTE(qB, vvB, crB, vaB);
            } else {
                COMPUTE(qB, vvB, crB, vaB);
                goto done;
            }
        }
        COMPUTE(qA, vvA, crA, vaA);
        done: ;
        #undef PRELOAD
        #undef COMPUTE
    }

    const float inv = (den != 0.f) ? 1.f / den : 0.f;
    // dims {2*lane, 2*lane+1} packed -> 64 lanes x u32 = one full 256B line
    *(unsigned int*)&ctx[(size_t)f * DD + 2 * lane] =
        ((unsigned int)f2b(acc1 * inv) << 16) | f2b(acc0 * inv);
}

// ---- K4: transpose ctx [NF][128] -> ctxT [128][NF] (bf16), full-line I/O both sides.
__global__ __launch_bounds__(256) void transpose_kernel(
    const unsigned short* __restrict__ ctx, unsigned short* __restrict__ ctxT)
{
    __shared__ unsigned int tile[64 * 33];   // [dpair][feat]: lo16=row 2d, hi16=row 2d+1
    const int t = threadIdx.x;
    const int f0 = blockIdx.x * 32;
    const int fl = t >> 3, db = t & 7;       // feature-local 0..31, dim-block (16 dims)
    const unsigned int* src = (const unsigned int*)&ctx[(size_t)(f0 + fl) * DD + db * 16];
    uint4 q0 = *(const uint4*)src;           // dims db*16+0..7 (u32 j: dims 2j,2j+1)
    uint4 q1 = *(const uint4*)(src + 4);     // dims db*16+8..15
    unsigned int w[8] = {q0.x, q0.y, q0.z, q0.w, q1.x, q1.y, q1.z, q1.w};
    #pragma unroll
    for (int j = 0; j < 8; ++j)
        tile[(db * 8 + j) * 33 + fl] = w[j];
    __syncthreads();

    const int r = t >> 1, side = t & 1;      // row 0..127, 16-feature half
    const int dpair = r >> 1, odd = r & 1;
    unsigned int o[8];
    #pragma unroll
    for (int i = 0; i < 8; ++i) {
        const int fo = side * 16 + i * 2;
        const unsigned int v0 = tile[dpair * 33 + fo];
        const unsigned int v1 = tile[dpair * 33 + fo + 1];
        o[i] = odd ? ((v1 & 0xFFFF0000u) | (v0 >> 16))
                   : ((v1 << 16) | (v0 & 0xFFFFu));
    }
    uint4 a = {o[0], o[1], o[2], o[3]}, b = {o[4], o[5], o[6], o[7]};
    *(uint4*)&ctxT[(size_t)r * NF + f0 + side * 16]     = a;
    *(uint4*)&ctxT[(size_t)r * NF + f0 + side * 16 + 8] = b;
}

// ---- K5: out[256,128] = values @ ctx via MFMA; values split hi/lo bf16 (exact).
__global__ __launch_bounds__(256) void outmm_kernel(
    const float* __restrict__ values, const unsigned short* __restrict__ ctxT,
    float* __restrict__ out)
{
    const int wave = threadIdx.x >> 6, lane = threadIdx.x & 63;
    const int m = lane & 15, quad = lane >> 4;
    const int mgroup = blockIdx.x & 3, kchunk = blockIdx.x >> 2;
    const int m0 = mgroup * 64 + wave * 16;
    const int k0 = kchunk * 160;

    f32x4 acc[8];
    #pragma unroll
    for (int nt = 0; nt < 8; ++nt) acc[nt] = (f32x4){0.f, 0.f, 0.f, 0.f};

    for (int ks = 0; ks < 5; ++ks) {
        const int kk = k0 + ks * 32 + quad * 8;
        const float* ap = &values[(size_t)(m0 + m) * NF + kk];
        float4 a0 = *(const float4*)ap;
        float4 a1 = *(const float4*)(ap + 4);
        float av[8] = {a0.x, a0.y, a0.z, a0.w, a1.x, a1.y, a1.z, a1.w};
        short8 ahi, alo;
        #pragma unroll
        for (int j = 0; j < 8; ++j) {
            unsigned short hv = f2b(av[j]);
            ahi[j] = (short)hv;
            alo[j] = (short)f2b(av[j] - b2f(hv));
        }
        #pragma unroll
        for (int nt = 0; nt < 8; ++nt) {
            short8 b = *(const short8*)&ctxT[(size_t)(nt * 16 + m) * NF + kk];
            acc[nt] = __builtin_amdgcn_mfma_f32_16x16x32_bf16(ahi, b, acc[nt], 0, 0, 0);
            acc[nt] = __builtin_amdgcn_mfma_f32_16x16x32_bf16(alo, b, acc[nt], 0, 0, 0);
        }
    }
    #pragma unroll
    for (int nt = 0; nt < 8; ++nt)
        #pragma unroll
        for (int r = 0; r < 4; ++r)
            atomicAdd(&out[(size_t)(m0 + quad * 4 + r) * DD + nt * 16 + m], acc[nt][r]);
}

extern "C" void kernel_launch(void* const* d_in, const int* in_sizes, int n_in,
                              void* d_out, int out_size, void* d_ws, size_t ws_size,
                              hipStream_t stream)
{
    const float* values  = (const float*)d_in[0];
    const float* featEmb = (const float*)d_in[1];
    const float* hidEmb  = (const float*)d_in[2];
    const float* wK      = (const float*)d_in[3];
    const float* wB      = (const float*)d_in[4];
    const float* uK      = (const float*)d_in[5];
    const float* corr    = (const float*)d_in[6];
    const int* cp        = (const int*)d_in[7];
    const int* fci       = (const int*)d_in[8];
    float* out = (float*)d_out;

    // ws layout (bytes, 16B-aligned):
    char* ws = (char*)d_ws;
    unsigned short* embB  = (unsigned short*)(ws);                   // 15,360,000
    unsigned short* P1b   = (unsigned short*)(ws + 15360000);        //  2,560,000
    unsigned short* P2b   = (unsigned short*)(ws + 17920000);        //  7,680,000
    unsigned short* ctx   = (unsigned short*)(ws + 25600000);        //  5,120,000
    unsigned short* ctxT  = (unsigned short*)(ws + 30720000);        //  5,120,000
    int*            rowptr= (int*)          (ws + 35840000);         //     80,004  (total ~35.9 MB)

    embproj_kernel  <<<938,  256, 0, stream>>>(featEmb, hidEmb, wK, wB, embB, P1b, P2b);
    rowptr_kernel   <<<2500, 256, 0, stream>>>(cp, rowptr);
    scorectx_kernel <<<2500, 512, 0, stream>>>(embB, P1b, P2b, uK, corr, rowptr, fci, ctx);
    transpose_kernel<<<625,  256, 0, stream>>>(ctx, ctxT);
    hipMemsetAsync(d_out, 0, (size_t)out_size * sizeof(float), stream);
    outmm_kernel    <<<500,  256, 0, stream>>>(values, ctxT, out);
}